// Round 1
// baseline (864.636 us; speedup 1.0000x reference)
//
#include <hip/hip_runtime.h>
#include <math.h>

#define N_ROWS 8192
#define IN_SZ 256
#define HID 128
#define INV_TEMP 5.0f
#define EPSV 1e-8f

// ---------------------------------------------------------------------------
// Kernel A: zp = ELU(z@W1 + b1)@W2 + b2, then L2-normalize rows.
// Block: 256 threads handles 64 rows. grid = (8192/64, 2) ; y selects mp/sc.
// ---------------------------------------------------------------------------
__global__ __launch_bounds__(256) void proj_norm_kernel(
    const float* __restrict__ z_mp, const float* __restrict__ z_sc,
    const float* __restrict__ W1, const float* __restrict__ b1,
    const float* __restrict__ W2, const float* __restrict__ b2,
    float* __restrict__ out_mp, float* __restrict__ out_sc)
{
    __shared__ float smem[12352];
    float* sZ  = smem;          // phase1: [k][m] 64x64
    float* sW  = smem + 4096;   // phase1: [k][c] 64x128
    float* sH  = smem;          // phase2: [h][m] 128x64 (reuses phase1 space)
    float* sW2 = smem + 8192;   // phase2: [k2][c] 32x128
    float* snorm = smem + 12288; // [64]

    const int t = threadIdx.x;
    const int tx = t & 15, ty = t >> 4;
    const int R0 = blockIdx.x * 64;
    const float* z = (blockIdx.y == 0) ? z_mp : z_sc;
    float* outp    = (blockIdx.y == 0) ? out_mp : out_sc;

    if (t < 64) snorm[t] = 0.f;

    // ---------------- GEMM1: H = ELU(Z @ W1 + b1) ----------------
    float acc[4][8];
#pragma unroll
    for (int i = 0; i < 4; ++i)
#pragma unroll
        for (int j = 0; j < 8; ++j) acc[i][j] = 0.f;

    for (int ch = 0; ch < 4; ++ch) {
        // stage Z tile transposed: sZ[k][m]
#pragma unroll
        for (int it = 0; it < 4; ++it) {
            int idx = it * 256 + t;        // 0..1023
            int m = idx >> 4;              // 0..63
            int k4 = idx & 15;
            float4 v = *(const float4*)(z + (size_t)(R0 + m) * IN_SZ + ch * 64 + k4 * 4);
            sZ[(k4 * 4 + 0) * 64 + m] = v.x;
            sZ[(k4 * 4 + 1) * 64 + m] = v.y;
            sZ[(k4 * 4 + 2) * 64 + m] = v.z;
            sZ[(k4 * 4 + 3) * 64 + m] = v.w;
        }
        // stage W1 chunk (natural layout [k][c])
#pragma unroll
        for (int it = 0; it < 8; ++it) {
            int idx = it * 256 + t;        // 0..2047
            int kk = idx >> 5;             // 0..63
            int c4 = idx & 31;
            *(float4*)(sW + kk * 128 + c4 * 4) =
                *(const float4*)(W1 + (size_t)(ch * 64 + kk) * 128 + c4 * 4);
        }
        __syncthreads();
#pragma unroll 8
        for (int k = 0; k < 64; ++k) {
            float4 a  = *(float4*)(sZ + k * 64 + ty * 4);
            float4 b0 = *(float4*)(sW + k * 128 + tx * 4);
            float4 b1v = *(float4*)(sW + k * 128 + 64 + tx * 4);
            float av[4] = {a.x, a.y, a.z, a.w};
            float bv[8] = {b0.x, b0.y, b0.z, b0.w, b1v.x, b1v.y, b1v.z, b1v.w};
#pragma unroll
            for (int i = 0; i < 4; ++i)
#pragma unroll
                for (int j = 0; j < 8; ++j)
                    acc[i][j] = fmaf(av[i], bv[j], acc[i][j]);
        }
        __syncthreads();
    }

    // bias + ELU, write H transposed into sH[h][m]
#pragma unroll
    for (int j = 0; j < 8; ++j) {
        int c = (j < 4) ? tx * 4 + j : 64 + tx * 4 + (j - 4);
        float bb = b1[c];
#pragma unroll
        for (int i = 0; i < 4; ++i) {
            float v = acc[i][j] + bb;
            v = (v > 0.f) ? v : expm1f(v);
            sH[c * 64 + (ty * 4 + i)] = v;
        }
    }

    // ---------------- GEMM2: O = H @ W2 + b2 ----------------
    float acc2[4][8];
#pragma unroll
    for (int i = 0; i < 4; ++i)
#pragma unroll
        for (int j = 0; j < 8; ++j) acc2[i][j] = 0.f;

    for (int ch2 = 0; ch2 < 4; ++ch2) {
#pragma unroll
        for (int it = 0; it < 4; ++it) {
            int idx = it * 256 + t;        // 0..1023
            int kk = idx >> 5;             // 0..31
            int c4 = idx & 31;
            *(float4*)(sW2 + kk * 128 + c4 * 4) =
                *(const float4*)(W2 + (size_t)(ch2 * 32 + kk) * 128 + c4 * 4);
        }
        __syncthreads();
#pragma unroll 8
        for (int k2 = 0; k2 < 32; ++k2) {
            float4 a  = *(float4*)(sH + (ch2 * 32 + k2) * 64 + ty * 4);
            float4 b0 = *(float4*)(sW2 + k2 * 128 + tx * 4);
            float4 b1v = *(float4*)(sW2 + k2 * 128 + 64 + tx * 4);
            float av[4] = {a.x, a.y, a.z, a.w};
            float bv[8] = {b0.x, b0.y, b0.z, b0.w, b1v.x, b1v.y, b1v.z, b1v.w};
#pragma unroll
            for (int i = 0; i < 4; ++i)
#pragma unroll
                for (int j = 0; j < 8; ++j)
                    acc2[i][j] = fmaf(av[i], bv[j], acc2[i][j]);
        }
        __syncthreads();
    }

    // bias, norm, scale, store
#pragma unroll
    for (int j = 0; j < 8; ++j) {
        int c = (j < 4) ? tx * 4 + j : 64 + tx * 4 + (j - 4);
        float bb = b2[c];
#pragma unroll
        for (int i = 0; i < 4; ++i) acc2[i][j] += bb;
    }
#pragma unroll
    for (int i = 0; i < 4; ++i) {
        float p = 0.f;
#pragma unroll
        for (int j = 0; j < 8; ++j) p = fmaf(acc2[i][j], acc2[i][j], p);
        atomicAdd(&snorm[ty * 4 + i], p);
    }
    __syncthreads();
#pragma unroll
    for (int i = 0; i < 4; ++i) {
        int r = ty * 4 + i;
        float scale = 1.f / fmaxf(sqrtf(snorm[r]), 1e-12f);
        float4 v0 = make_float4(acc2[i][0] * scale, acc2[i][1] * scale,
                                acc2[i][2] * scale, acc2[i][3] * scale);
        float4 v1 = make_float4(acc2[i][4] * scale, acc2[i][5] * scale,
                                acc2[i][6] * scale, acc2[i][7] * scale);
        *(float4*)(outp + (size_t)(R0 + r) * HID + tx * 4) = v0;
        *(float4*)(outp + (size_t)(R0 + r) * HID + 64 + tx * 4) = v1;
    }
}

// ---------------------------------------------------------------------------
// Kernel B: 128x128 sim tile per block; accumulate row/col (pos-weighted) sums.
// sums layout: [0:8192) rowsum, [8192) rowpos, [16384) colsum, [24576) colpos
// ---------------------------------------------------------------------------
__global__ __launch_bounds__(256) void sim_reduce_kernel(
    const float* __restrict__ mpn, const float* __restrict__ scn,
    const int* __restrict__ pos, float* __restrict__ sums)
{
    __shared__ float smem[16384];
    float* sA = smem;           // [k][m] 64x128 chunk of mp_norm^T
    float* sB = smem + 8192;    // [k][n] 64x128 chunk of sc_norm^T
    float* red = smem;          // after compute: 4 x 128 reduction arrays

    const int t = threadIdx.x;
    const int tx = t & 15, ty = t >> 4;
    const int I = blockIdx.x * 128;
    const int J = blockIdx.y * 128;

    float acc[8][8];
#pragma unroll
    for (int i = 0; i < 8; ++i)
#pragma unroll
        for (int j = 0; j < 8; ++j) acc[i][j] = 0.f;

    for (int ch = 0; ch < 2; ++ch) {
#pragma unroll
        for (int it = 0; it < 8; ++it) {
            int idx = it * 256 + t;    // 0..2047
            int m = idx >> 4;          // 0..127
            int k4 = idx & 15;
            float4 va = *(const float4*)(mpn + (size_t)(I + m) * HID + ch * 64 + k4 * 4);
            sA[(k4 * 4 + 0) * 128 + m] = va.x;
            sA[(k4 * 4 + 1) * 128 + m] = va.y;
            sA[(k4 * 4 + 2) * 128 + m] = va.z;
            sA[(k4 * 4 + 3) * 128 + m] = va.w;
            float4 vb = *(const float4*)(scn + (size_t)(J + m) * HID + ch * 64 + k4 * 4);
            sB[(k4 * 4 + 0) * 128 + m] = vb.x;
            sB[(k4 * 4 + 1) * 128 + m] = vb.y;
            sB[(k4 * 4 + 2) * 128 + m] = vb.z;
            sB[(k4 * 4 + 3) * 128 + m] = vb.w;
        }
        __syncthreads();
#pragma unroll 8
        for (int k = 0; k < 64; ++k) {
            float4 a0 = *(float4*)(sA + k * 128 + ty * 4);
            float4 a1 = *(float4*)(sA + k * 128 + 64 + ty * 4);
            float4 b0 = *(float4*)(sB + k * 128 + tx * 4);
            float4 b1 = *(float4*)(sB + k * 128 + 64 + tx * 4);
            float av[8] = {a0.x, a0.y, a0.z, a0.w, a1.x, a1.y, a1.z, a1.w};
            float bv[8] = {b0.x, b0.y, b0.z, b0.w, b1.x, b1.y, b1.z, b1.w};
#pragma unroll
            for (int i = 0; i < 8; ++i)
#pragma unroll
                for (int j = 0; j < 8; ++j)
                    acc[i][j] = fmaf(av[i], bv[j], acc[i][j]);
        }
        __syncthreads();
    }

    // sim = exp(dot / T), in place
#pragma unroll
    for (int i = 0; i < 8; ++i)
#pragma unroll
        for (int j = 0; j < 8; ++j)
            acc[i][j] = __expf(acc[i][j] * INV_TEMP);

    // zero reduction arrays (512 floats) in reused LDS
    red[t] = 0.f;
    red[256 + t] = 0.f;
    __syncthreads();

    // row accumulation: rowsum / rowpos (pos[i,j])
#pragma unroll
    for (int i = 0; i < 8; ++i) {
        int m = (i < 4) ? ty * 4 + i : 64 + ty * 4 + (i - 4);
        const int4 p0 = *(const int4*)(pos + (size_t)(I + m) * N_ROWS + J + tx * 4);
        const int4 p1 = *(const int4*)(pos + (size_t)(I + m) * N_ROWS + J + 64 + tx * 4);
        float rs = acc[i][0] + acc[i][1] + acc[i][2] + acc[i][3]
                 + acc[i][4] + acc[i][5] + acc[i][6] + acc[i][7];
        float rp = 0.f;
        rp += p0.x ? acc[i][0] : 0.f;
        rp += p0.y ? acc[i][1] : 0.f;
        rp += p0.z ? acc[i][2] : 0.f;
        rp += p0.w ? acc[i][3] : 0.f;
        rp += p1.x ? acc[i][4] : 0.f;
        rp += p1.y ? acc[i][5] : 0.f;
        rp += p1.z ? acc[i][6] : 0.f;
        rp += p1.w ? acc[i][7] : 0.f;
        atomicAdd(&red[m], rs);
        atomicAdd(&red[128 + m], rp);
    }

    // col accumulation: colsum / colpos (pos[col, row] i.e. transposed read)
#pragma unroll
    for (int j = 0; j < 8; ++j) {
        int n = (j < 4) ? tx * 4 + j : 64 + tx * 4 + (j - 4);
        const int4 q0 = *(const int4*)(pos + (size_t)(J + n) * N_ROWS + I + ty * 4);
        const int4 q1 = *(const int4*)(pos + (size_t)(J + n) * N_ROWS + I + 64 + ty * 4);
        float cs = acc[0][j] + acc[1][j] + acc[2][j] + acc[3][j]
                 + acc[4][j] + acc[5][j] + acc[6][j] + acc[7][j];
        float cp = 0.f;
        cp += q0.x ? acc[0][j] : 0.f;
        cp += q0.y ? acc[1][j] : 0.f;
        cp += q0.z ? acc[2][j] : 0.f;
        cp += q0.w ? acc[3][j] : 0.f;
        cp += q1.x ? acc[4][j] : 0.f;
        cp += q1.y ? acc[5][j] : 0.f;
        cp += q1.z ? acc[6][j] : 0.f;
        cp += q1.w ? acc[7][j] : 0.f;
        atomicAdd(&red[256 + n], cs);
        atomicAdd(&red[384 + n], cp);
    }
    __syncthreads();

    if (t < 128) {
        atomicAdd(&sums[I + t],              red[t]);
        atomicAdd(&sums[N_ROWS + I + t],     red[128 + t]);
        atomicAdd(&sums[2 * N_ROWS + J + t], red[256 + t]);
        atomicAdd(&sums[3 * N_ROWS + J + t], red[384 + t]);
    }
}

// ---------------------------------------------------------------------------
// Kernel C: final loss per element
// ---------------------------------------------------------------------------
__global__ __launch_bounds__(256) void finish_kernel(
    const float* __restrict__ sums, float* __restrict__ out)
{
    int i = blockIdx.x * 256 + threadIdx.x;
    if (i >= N_ROWS) return;
    float rsv = sums[i];
    float rpv = sums[N_ROWS + i];
    float csv = sums[2 * N_ROWS + i];
    float cpv = sums[3 * N_ROWS + i];
    float lmp = -logf(rpv / (rsv + EPSV) + EPSV);
    float lsc = -logf(cpv / (csv + EPSV) + EPSV);
    float a = 0.5f * lmp + 0.5f * lsc;
    if (!isfinite(a)) a = 0.f;
    out[i] = a;
}

extern "C" void kernel_launch(void* const* d_in, const int* in_sizes, int n_in,
                              void* d_out, int out_size, void* d_ws, size_t ws_size,
                              hipStream_t stream) {
    const float* z_mp = (const float*)d_in[0];
    const float* z_sc = (const float*)d_in[1];
    const float* W1   = (const float*)d_in[2];
    const float* b1   = (const float*)d_in[3];
    const float* W2   = (const float*)d_in[4];
    const float* b2   = (const float*)d_in[5];
    const int*   pos  = (const int*)d_in[6];
    float* out = (float*)d_out;

    float* ws  = (float*)d_ws;
    float* mpn = ws;                                    // 8192*128
    float* scn = ws + (size_t)N_ROWS * HID;             // 8192*128
    float* sums = ws + (size_t)2 * N_ROWS * HID;        // 4*8192

    hipMemsetAsync(sums, 0, (size_t)4 * N_ROWS * sizeof(float), stream);
    proj_norm_kernel<<<dim3(N_ROWS / 64, 2), 256, 0, stream>>>(
        z_mp, z_sc, W1, b1, W2, b2, mpn, scn);
    sim_reduce_kernel<<<dim3(64, 64), 256, 0, stream>>>(mpn, scn, pos, sums);
    finish_kernel<<<N_ROWS / 256, 256, 0, stream>>>(sums, out);
}

// Round 2
// 529.769 us; speedup vs baseline: 1.6321x; 1.6321x over previous
//
#include <hip/hip_runtime.h>
#include <math.h>

#define N_ROWS 8192
#define IN_SZ 256
#define HID 128
#define INV_TEMP 5.0f
#define EPSV 1e-8f

typedef short short8 __attribute__((ext_vector_type(8)));
typedef float f32x4 __attribute__((ext_vector_type(4)));

__device__ __forceinline__ ushort f2bf(float v) {
    unsigned b = __float_as_uint(v);
    return (ushort)((b + 0x7FFFu + ((b >> 16) & 1u)) >> 16);
}
__device__ __forceinline__ float bf2f(ushort u) {
    return __uint_as_float(((unsigned)u) << 16);
}

// ---------------------------------------------------------------------------
// Kernel A: zp = ELU(z@W1 + b1)@W2 + b2, L2-normalize rows, emit bf16 hi/lo.
// 32 rows per block, 512 blocks (2/CU). Padded LDS strides (34/33) to avoid
// the 16-way staging conflicts of the previous version.
// ---------------------------------------------------------------------------
__global__ __launch_bounds__(256) void proj_norm_kernel(
    const float* __restrict__ z_mp, const float* __restrict__ z_sc,
    const float* __restrict__ W1, const float* __restrict__ b1,
    const float* __restrict__ W2, const float* __restrict__ b2,
    ushort* __restrict__ h_mp, ushort* __restrict__ l_mp,
    ushort* __restrict__ h_sc, ushort* __restrict__ l_sc)
{
    __shared__ float smem[10368];
    float* sZ  = smem;           // phase1: [k][m] 64 x 34 (pad)
    float* sW  = smem + 2176;    // phase1: [k][c] 64 x 128
    float* sH  = smem;           // phase2: [c][m] 128 x 33 (pad)
    float* sW2 = smem + 4224;    // phase2: [k2][c] 32 x 128
    float* snorm = smem + 8320;  // [32]

    const int t = threadIdx.x;
    const int tx = t & 15, ty = t >> 4;       // ty: 16 row-pairs, tx: col groups
    const int R0 = blockIdx.x * 32;
    const float* z = (blockIdx.y == 0) ? z_mp : z_sc;
    ushort* outH   = (blockIdx.y == 0) ? h_mp : h_sc;
    ushort* outL   = (blockIdx.y == 0) ? l_mp : l_sc;

    if (t < 32) snorm[t] = 0.f;

    float acc[2][8];
#pragma unroll
    for (int i = 0; i < 2; ++i)
#pragma unroll
        for (int j = 0; j < 8; ++j) acc[i][j] = 0.f;

    // ---------------- GEMM1: H = ELU(Z @ W1 + b1) ----------------
    for (int ch = 0; ch < 4; ++ch) {
#pragma unroll
        for (int it = 0; it < 2; ++it) {
            int idx = it * 256 + t;        // 0..511
            int k4 = idx >> 5;             // 0..15
            int m  = idx & 31;
            float4 v = *(const float4*)(z + (size_t)(R0 + m) * IN_SZ + ch * 64 + k4 * 4);
            sZ[(k4 * 4 + 0) * 34 + m] = v.x;
            sZ[(k4 * 4 + 1) * 34 + m] = v.y;
            sZ[(k4 * 4 + 2) * 34 + m] = v.z;
            sZ[(k4 * 4 + 3) * 34 + m] = v.w;
        }
#pragma unroll
        for (int it = 0; it < 8; ++it) {
            int idx = it * 256 + t;        // 0..2047
            int kk = idx >> 5;             // 0..63
            int c4 = idx & 31;
            *(float4*)(sW + kk * 128 + c4 * 4) =
                *(const float4*)(W1 + (size_t)(ch * 64 + kk) * HID + c4 * 4);
        }
        __syncthreads();
#pragma unroll 8
        for (int k = 0; k < 64; ++k) {
            float2 a = *(const float2*)(sZ + k * 34 + ty * 2);
            float4 b0 = *(float4*)(sW + k * 128 + tx * 4);
            float4 b1v = *(float4*)(sW + k * 128 + 64 + tx * 4);
            float av[2] = {a.x, a.y};
            float bv[8] = {b0.x, b0.y, b0.z, b0.w, b1v.x, b1v.y, b1v.z, b1v.w};
#pragma unroll
            for (int i = 0; i < 2; ++i)
#pragma unroll
                for (int j = 0; j < 8; ++j)
                    acc[i][j] = fmaf(av[i], bv[j], acc[i][j]);
        }
        __syncthreads();
    }

    // bias + ELU -> sH[c][m]
#pragma unroll
    for (int j = 0; j < 8; ++j) {
        int c = (j < 4) ? tx * 4 + j : 64 + tx * 4 + (j - 4);
        float bb = b1[c];
#pragma unroll
        for (int i = 0; i < 2; ++i) {
            float v = acc[i][j] + bb;
            v = (v > 0.f) ? v : expm1f(v);
            sH[c * 33 + ty * 2 + i] = v;
        }
    }

    // ---------------- GEMM2: O = H @ W2 + b2 ----------------
    float acc2[2][8];
#pragma unroll
    for (int i = 0; i < 2; ++i)
#pragma unroll
        for (int j = 0; j < 8; ++j) acc2[i][j] = 0.f;

    for (int ch2 = 0; ch2 < 4; ++ch2) {
#pragma unroll
        for (int it = 0; it < 4; ++it) {
            int idx = it * 256 + t;        // 0..1023
            int kk = idx >> 5;             // 0..31
            int c4 = idx & 31;
            *(float4*)(sW2 + kk * 128 + c4 * 4) =
                *(const float4*)(W2 + (size_t)(ch2 * 32 + kk) * HID + c4 * 4);
        }
        __syncthreads();
#pragma unroll 8
        for (int k2 = 0; k2 < 32; ++k2) {
            float a0 = sH[(ch2 * 32 + k2) * 33 + ty * 2];
            float a1 = sH[(ch2 * 32 + k2) * 33 + ty * 2 + 1];
            float4 b0 = *(float4*)(sW2 + k2 * 128 + tx * 4);
            float4 b1v = *(float4*)(sW2 + k2 * 128 + 64 + tx * 4);
            float av[2] = {a0, a1};
            float bv[8] = {b0.x, b0.y, b0.z, b0.w, b1v.x, b1v.y, b1v.z, b1v.w};
#pragma unroll
            for (int i = 0; i < 2; ++i)
#pragma unroll
                for (int j = 0; j < 8; ++j)
                    acc2[i][j] = fmaf(av[i], bv[j], acc2[i][j]);
        }
        __syncthreads();
    }

    // bias, norm, scale, bf16 hi/lo split, store
#pragma unroll
    for (int j = 0; j < 8; ++j) {
        int c = (j < 4) ? tx * 4 + j : 64 + tx * 4 + (j - 4);
        float bb = b2[c];
#pragma unroll
        for (int i = 0; i < 2; ++i) acc2[i][j] += bb;
    }
#pragma unroll
    for (int i = 0; i < 2; ++i) {
        float p = 0.f;
#pragma unroll
        for (int j = 0; j < 8; ++j) p = fmaf(acc2[i][j], acc2[i][j], p);
        atomicAdd(&snorm[ty * 2 + i], p);
    }
    __syncthreads();
#pragma unroll
    for (int i = 0; i < 2; ++i) {
        int r = ty * 2 + i;
        float scale = 1.f / fmaxf(sqrtf(snorm[r]), 1e-12f);
#pragma unroll
        for (int half = 0; half < 2; ++half) {
            ushort4 h4, l4;
            ushort hu[4], lu[4];
#pragma unroll
            for (int j = 0; j < 4; ++j) {
                float v = acc2[i][half * 4 + j] * scale;
                ushort hb = f2bf(v);
                float lv = v - bf2f(hb);
                hu[j] = hb;
                lu[j] = f2bf(lv);
            }
            h4.x = hu[0]; h4.y = hu[1]; h4.z = hu[2]; h4.w = hu[3];
            l4.x = lu[0]; l4.y = lu[1]; l4.z = lu[2]; l4.w = lu[3];
            size_t off = (size_t)(R0 + r) * HID + half * 64 + tx * 4;
            *(ushort4*)(outH + off) = h4;
            *(ushort4*)(outL + off) = l4;
        }
    }
}

// ---------------------------------------------------------------------------
// Kernel B: MFMA sim tile 128x128 per block, bf16 hi/lo split (3-term),
// fragments loaded straight from global (L2/L3-resident, 8 MB total).
// Wave w (2x2 quadrants of 64x64) -> 4x4 subtiles of 16x16, K=128.
// Reductions: col sums from C-layout regs + shfl_xor; row sums via per-wave
// LDS transpose (16x68 padded). pos read in both orientations (coalesced /
// line-consumed 16B granules).
// ---------------------------------------------------------------------------
__global__ __launch_bounds__(256) void sim_mfma_kernel(
    const ushort* __restrict__ mh_, const ushort* __restrict__ ml_,
    const ushort* __restrict__ sh_, const ushort* __restrict__ sl_,
    const int* __restrict__ pos, float* __restrict__ sums)
{
    __shared__ float redR[128], redRP[128], redC[128], redCP[128];
    __shared__ float tbuf[4][16 * 68];

    const int t = threadIdx.x;
    const int lane = t & 63;
    const int wave = t >> 6;                 // 0..3
    const int wr = wave >> 1, wc = wave & 1; // quadrant coords
    const int I = blockIdx.y * 128;
    const int J = blockIdx.x * 128;
    const int r0 = wr * 64, c0 = wc * 64;
    const int lrow = lane & 15;
    const int quad = lane >> 4;              // 0..3

    if (t < 128) { redR[t] = 0.f; redRP[t] = 0.f; }
    else { redC[t - 128] = 0.f; redCP[t - 128] = 0.f; }
    __syncthreads();

    const short* mh = (const short*)mh_;
    const short* ml = (const short*)ml_;
    const short* sh = (const short*)sh_;
    const short* sl = (const short*)sl_;

    size_t aoff[4], boff[4];
#pragma unroll
    for (int s = 0; s < 4; ++s) {
        aoff[s] = (size_t)(I + r0 + s * 16 + lrow) * HID + quad * 8;
        boff[s] = (size_t)(J + c0 + s * 16 + lrow) * HID + quad * 8;
    }

    f32x4 acc[4][4];
#pragma unroll
    for (int si = 0; si < 4; ++si)
#pragma unroll
        for (int sj = 0; sj < 4; ++sj) acc[si][sj] = (f32x4)0.f;

    // K loop: 4 ksteps of 32 (fully unrolled)
#pragma unroll
    for (int ks = 0; ks < 4; ++ks) {
        short8 ah[4], al[4], bh[4], bl[4];
#pragma unroll
        for (int s = 0; s < 4; ++s) {
            ah[s] = *(const short8*)(mh + aoff[s] + ks * 32);
            al[s] = *(const short8*)(ml + aoff[s] + ks * 32);
            bh[s] = *(const short8*)(sh + boff[s] + ks * 32);
            bl[s] = *(const short8*)(sl + boff[s] + ks * 32);
        }
#pragma unroll
        for (int si = 0; si < 4; ++si)
#pragma unroll
            for (int sj = 0; sj < 4; ++sj) {
                acc[si][sj] = __builtin_amdgcn_mfma_f32_16x16x32_bf16(
                    ah[si], bh[sj], acc[si][sj], 0, 0, 0);
                acc[si][sj] = __builtin_amdgcn_mfma_f32_16x16x32_bf16(
                    ah[si], bl[sj], acc[si][sj], 0, 0, 0);
                acc[si][sj] = __builtin_amdgcn_mfma_f32_16x16x32_bf16(
                    al[si], bh[sj], acc[si][sj], 0, 0, 0);
            }
    }

    // sim = exp(dot / T) in place
#pragma unroll
    for (int si = 0; si < 4; ++si)
#pragma unroll
        for (int sj = 0; sj < 4; ++sj)
#pragma unroll
            for (int r = 0; r < 4; ++r)
                acc[si][sj][r] = __expf(acc[si][sj][r] * INV_TEMP);

    // ---- column sums (C-layout: col = lane&15, row = quad*4+reg) ----
    // colsum_J[n] = sum_m S[m][n]; colpos uses pos[J+n][I+m] (transposed tile)
#pragma unroll
    for (int sj = 0; sj < 4; ++sj) {
        int n = c0 + sj * 16 + lrow;  // col within tile
        float cs = 0.f, cp = 0.f;
#pragma unroll
        for (int si = 0; si < 4; ++si) {
            f32x4 v = acc[si][sj];
            cs += v[0] + v[1] + v[2] + v[3];
            const int4 p = *(const int4*)(pos + (size_t)(J + n) * N_ROWS
                                          + I + r0 + si * 16 + quad * 4);
            cp += (p.x ? v[0] : 0.f) + (p.y ? v[1] : 0.f)
                + (p.z ? v[2] : 0.f) + (p.w ? v[3] : 0.f);
        }
        cs += __shfl_xor(cs, 16); cs += __shfl_xor(cs, 32);
        cp += __shfl_xor(cp, 16); cp += __shfl_xor(cp, 32);
        if (lane < 16) {
            atomicAdd(&redC[c0 + sj * 16 + lane], cs);
            atomicAdd(&redCP[c0 + sj * 16 + lane], cp);
        }
    }

    // ---- row sums via per-wave LDS transpose (16 rows x 64 cols, pad 68) ----
    float* tw = tbuf[wave];
#pragma unroll
    for (int si = 0; si < 4; ++si) {
#pragma unroll
        for (int sj = 0; sj < 4; ++sj)
#pragma unroll
            for (int r = 0; r < 4; ++r)
                tw[(quad * 4 + r) * 68 + sj * 16 + lrow] = acc[si][sj][r];
        // same-wave LDS: ds ops process in program order; compiler orders
        // may-aliasing accesses to the same __shared__ array.
        int row = lane & 15;        // row within 16-row strip
        int chunk = lane >> 2 >> 2; // lane>>4: 0..3, 16-col chunk
        const int* prow = pos + (size_t)(I + r0 + si * 16 + row) * N_ROWS
                        + J + c0 + chunk * 16;
        float rs = 0.f, rp = 0.f;
#pragma unroll
        for (int c4 = 0; c4 < 4; ++c4) {
            f32x4 v = *(const f32x4*)(tw + row * 68 + chunk * 16 + c4 * 4);
            const int4 p = *(const int4*)(prow + c4 * 4);
            rs += v[0] + v[1] + v[2] + v[3];
            rp += (p.x ? v[0] : 0.f) + (p.y ? v[1] : 0.f)
                + (p.z ? v[2] : 0.f) + (p.w ? v[3] : 0.f);
        }
        rs += __shfl_xor(rs, 16); rs += __shfl_xor(rs, 32);
        rp += __shfl_xor(rp, 16); rp += __shfl_xor(rp, 32);
        if (lane < 16) {
            atomicAdd(&redR[r0 + si * 16 + lane], rs);
            atomicAdd(&redRP[r0 + si * 16 + lane], rp);
        }
    }
    __syncthreads();

    if (t < 128) {
        atomicAdd(&sums[I + t],              redR[t]);
        atomicAdd(&sums[N_ROWS + I + t],     redRP[t]);
        atomicAdd(&sums[2 * N_ROWS + J + t], redC[t]);
        atomicAdd(&sums[3 * N_ROWS + J + t], redCP[t]);
    }
}

// ---------------------------------------------------------------------------
// Kernel C: final loss per element
// ---------------------------------------------------------------------------
__global__ __launch_bounds__(256) void finish_kernel(
    const float* __restrict__ sums, float* __restrict__ out)
{
    int i = blockIdx.x * 256 + threadIdx.x;
    if (i >= N_ROWS) return;
    float rsv = sums[i];
    float rpv = sums[N_ROWS + i];
    float csv = sums[2 * N_ROWS + i];
    float cpv = sums[3 * N_ROWS + i];
    float lmp = -logf(rpv / (rsv + EPSV) + EPSV);
    float lsc = -logf(cpv / (csv + EPSV) + EPSV);
    float a = 0.5f * lmp + 0.5f * lsc;
    if (!isfinite(a)) a = 0.f;
    out[i] = a;
}

extern "C" void kernel_launch(void* const* d_in, const int* in_sizes, int n_in,
                              void* d_out, int out_size, void* d_ws, size_t ws_size,
                              hipStream_t stream) {
    const float* z_mp = (const float*)d_in[0];
    const float* z_sc = (const float*)d_in[1];
    const float* W1   = (const float*)d_in[2];
    const float* b1   = (const float*)d_in[3];
    const float* W2   = (const float*)d_in[4];
    const float* b2   = (const float*)d_in[5];
    const int*   pos  = (const int*)d_in[6];
    float* out = (float*)d_out;

    ushort* wsu = (ushort*)d_ws;
    const size_t NV = (size_t)N_ROWS * HID;          // 1,048,576 elements
    ushort* mh = wsu;
    ushort* ml = wsu + NV;
    ushort* sh = wsu + 2 * NV;
    ushort* sl = wsu + 3 * NV;
    float* sums = (float*)(wsu + 4 * NV);            // 4*8192 floats

    hipMemsetAsync(sums, 0, (size_t)4 * N_ROWS * sizeof(float), stream);
    proj_norm_kernel<<<dim3(N_ROWS / 32, 2), 256, 0, stream>>>(
        z_mp, z_sc, W1, b1, W2, b2, mh, ml, sh, sl);
    sim_mfma_kernel<<<dim3(64, 64), 256, 0, stream>>>(mh, ml, sh, sl, pos, sums);
    finish_kernel<<<N_ROWS / 256, 256, 0, stream>>>(sums, out);
}